// Round 10
// baseline (1584.015 us; speedup 1.0000x reference)
//
#include <hip/hip_runtime.h>
#include <hip/hip_bf16.h>
#include <cstdint>
#include <math.h>

#define N_TOK 8192
#define D_DIM 1024
#define F_DIM 4096
#define NE 8
#define CAP 8192
#define MAXT 136   // max sum_e ceil(cnt_e/128) = 135, padded

typedef __attribute__((ext_vector_type(8))) short short8;
typedef __attribute__((ext_vector_type(4))) short short4v;
typedef __attribute__((ext_vector_type(4))) float f32x4;

__device__ __forceinline__ short f2bf(float f) {
  __bf16 b = (__bf16)f;
  return *(short*)&b;
}
__device__ __forceinline__ float bf2f(short u) {
  union { unsigned int i; float f; } c;
  c.i = ((unsigned int)(unsigned short)u) << 16;
  return c.f;
}
__device__ __forceinline__ int sw(int r) { return (r & 3) ^ ((r >> 2) & 3); }
__device__ __forceinline__ void gload(const void* g, void* l) {
  __builtin_amdgcn_global_load_lds(
      (const __attribute__((address_space(1))) uint32_t*)g,
      (__attribute__((address_space(3))) uint32_t*)l, 16, 0, 0);
}

// Packed tile formats (byte layouts identical in global and LDS):
//  A tile: 128 rows x 32 K = 8 KB:  byte = r*64 + ((((k>>3)&3) ^ sw(r))<<4) + (k&7)*2
//  B tile: 256 rows x 32 K = 16 KB: same formula, r = n&255
// Full-wave ds_read_b128 bank tally with this swizzle = exactly 8/bank (free).

// ---------------- gating ----------------------------------------------------
__global__ __launch_bounds__(256) void gate_kernel(
    const float* __restrict__ X, const float* __restrict__ Wg,
    const float* __restrict__ bg, int* __restrict__ cnt,
    int* __restrict__ bucket, float* __restrict__ pairw)
{
  const int token = blockIdx.x;
  const int tid = threadIdx.x;
  const float4* x4 = (const float4*)(X + (size_t)token * D_DIM);
  const float4* wg4 = (const float4*)Wg;
  float part[NE];
#pragma unroll
  for (int e = 0; e < NE; ++e) part[e] = 0.f;
  const float4 xv = x4[tid];
#pragma unroll
  for (int e = 0; e < NE; ++e) {
    const float4 wv = wg4[e * (D_DIM / 4) + tid];
    part[e] = fmaf(xv.x, wv.x, fmaf(xv.y, wv.y, fmaf(xv.z, wv.z, fmaf(xv.w, wv.w, part[e]))));
  }
#pragma unroll
  for (int e = 0; e < NE; ++e) {
#pragma unroll
    for (int off = 32; off > 0; off >>= 1) part[e] += __shfl_down(part[e], off);
  }
  __shared__ float wsum[4][NE];
  const int wave = tid >> 6;
  if ((tid & 63) == 0) {
#pragma unroll
    for (int e = 0; e < NE; ++e) wsum[wave][e] = part[e];
  }
  __syncthreads();
  if (tid == 0) {
    float lg[NE];
#pragma unroll
    for (int e = 0; e < NE; ++e)
      lg[e] = wsum[0][e] + wsum[1][e] + wsum[2][e] + wsum[3][e] + bg[e];
    int e0 = 0;
#pragma unroll
    for (int e = 1; e < NE; ++e) if (lg[e] > lg[e0]) e0 = e;     // jax tie-break: lower idx
    int e1 = (e0 == 0) ? 1 : 0;
#pragma unroll
    for (int e = 0; e < NE; ++e) if (e != e0 && lg[e] > lg[e1]) e1 = e;
    float p1 = expf(lg[e1] - lg[e0]);            // p0 = 1; softmax denom cancels
    float inv = 1.f / (1.f + p1);
    pairw[token * 2]     = inv;
    pairw[token * 2 + 1] = p1 * inv;
    int pos0 = atomicAdd(&cnt[e0], 1);
    bucket[e0 * CAP + pos0] = token * 2;
    int pos1 = atomicAdd(&cnt[e1], 1);
    bucket[e1 * CAP + pos1] = token * 2 + 1;
  }
}

// ---------------- prefix sums (row offsets + 128-row tile offsets) ----------
__global__ void prefix_kernel(const int* __restrict__ cnt,
                              int* __restrict__ expoff, int* __restrict__ toff)
{
  if (threadIdx.x == 0 && blockIdx.x == 0) {
    int s = 0, t = 0;
#pragma unroll
    for (int e = 0; e < NE; ++e) {
      expoff[e] = s;
      toff[e] = t;
      s += cnt[e];
      t += (cnt[e] + 127) >> 7;
    }
    toff[NE] = t;
  }
}

// ---------------- inverse map: pair -> slot ---------------------------------
__global__ __launch_bounds__(256) void fillslot_kernel(
    const int* __restrict__ cnt, const int* __restrict__ expoff,
    const int* __restrict__ bucket, int* __restrict__ pairslot)
{
  const int e = blockIdx.x;
  const int n = cnt[e], off = expoff[e];
  for (int p = threadIdx.x; p < n; p += 256)
    pairslot[bucket[e * CAP + p]] = off + p;
}

// ---------------- pregather: X fp32 rows -> packed bf16 A tiles -------------
// grid (mt, kc): 128 rows x 256 K per block. Thread: r = tid&127, kh = tid>>7.
__global__ __launch_bounds__(256) void pregather_kernel(
    const float* __restrict__ X, const int* __restrict__ cnt,
    const int* __restrict__ toff, const int* __restrict__ bucket,
    unsigned short* __restrict__ XbP)
{
  const int mt = blockIdx.x;
  const int kc = blockIdx.y;
  if (mt >= toff[NE]) return;
  int e = 0;
  while (mt >= toff[e + 1]) ++e;
  const int mtile = mt - toff[e];
  const int cnt_e = cnt[e];
  const int tid = threadIdx.x;
  const int r = tid & 127, kh = tid >> 7;
  const int pos = mtile * 128 + r;
  const int pair = (pos < cnt_e) ? bucket[e * CAP + pos] : 0;
  const size_t token = (size_t)(pair >> 1);
  const int k0 = kc * 256 + kh * 128;
  const float* src = X + token * D_DIM + k0;
  char* dst = (char*)XbP;
  const int swr = sw(r) << 4;
#pragma unroll
  for (int kk = 0; kk < 128; kk += 4) {
    const float4 v = *(const float4*)(src + kk);
    short4v o;
    o.x = f2bf(v.x); o.y = f2bf(v.y); o.z = f2bf(v.z); o.w = f2bf(v.w);
    const int k = k0 + kk;
    const size_t byte = ((size_t)mt * 32 + (k >> 5)) * 8192 + r * 64 +
                        (((((k >> 3) & 3) << 4) ^ swr)) + (k & 7) * 2;
    *(short4v*)(dst + byte) = o;
  }
}

// ---------------- pack weights: fp32 [R=K][C=N] -> packed B tiles -----------
__global__ __launch_bounds__(256) void pack_kernel(
    const float* __restrict__ src, unsigned short* __restrict__ dst, int R, int C)
{
  __shared__ float tileT[64][68];
  const int ez = blockIdx.z;
  src += (size_t)ez * R * C;
  char* dbytes = (char*)dst + (size_t)ez * R * C * 2;
  const int c0 = blockIdx.x * 64, r0 = blockIdx.y * 64;
  const int tid = threadIdx.x;
  const int cx = tid & 15;
  const int ry = tid >> 4;
#pragma unroll
  for (int i = 0; i < 4; ++i) {
    const int row = ry + i * 16;
    const float4 v = *(const float4*)(src + (size_t)(r0 + row) * C + c0 + cx * 4);
    tileT[cx * 4 + 0][row] = v.x;
    tileT[cx * 4 + 1][row] = v.y;
    tileT[cx * 4 + 2][row] = v.z;
    tileT[cx * 4 + 3][row] = v.w;
  }
  __syncthreads();
#pragma unroll
  for (int i = 0; i < 4; ++i) {
    const int cc = ry + i * 16;
    const int n = c0 + cc;                 // N dim (tile row)
    const int k = r0 + cx * 4;             // K dim
    const float4 v = *(const float4*)(&tileT[cc][cx * 4]);
    short4v o;
    o.x = f2bf(v.x); o.y = f2bf(v.y); o.z = f2bf(v.z); o.w = f2bf(v.w);
    const int nt = n >> 8, r = n & 255;
    const size_t byte = ((size_t)nt * (R >> 5) + (k >> 5)) * 16384 + r * 64 +
                        ((((k >> 3) & 3) ^ sw(r)) << 4) + (k & 7) * 2;
    *(short4v*)(dbytes + byte) = o;
  }
}

// ---------------- grouped expert GEMM: 128x256xBK32, 3 blocks/CU ------------
// 4 waves side-by-side in N (wave = 128M x 64N, acc[8][4]); LDS 48 KB dbuf ->
// 3 independent barrier groups per CU (the staging-throughput lever).
// LAYER 1: hmidP[mt tiles] = gelu(XbP @ W1p + b1); KT=32.
// LAYER 2 (split-K=2): ybufA/B[slot] = hmidP @ W2p (+b2 in split 0); KT=64.
template<int LAYER>
__global__ __launch_bounds__(256) void moe_gemm(
    const unsigned short* __restrict__ Apack,
    const unsigned short* __restrict__ Bpack,
    const float* __restrict__ bias,
    const int* __restrict__ cnt,
    const int* __restrict__ expoff,
    const int* __restrict__ toff,
    unsigned short* __restrict__ OutP,      // hmidP (L1) / ybufA (L2)
    unsigned short* __restrict__ OutP2)     // ybufB (L2)
{
  constexpr int KDIM = (LAYER == 1) ? D_DIM : F_DIM;
  constexpr int NDIM = (LAYER == 1) ? F_DIM : D_DIM;
  constexpr int KT = (LAYER == 1) ? 32 : 64;          // K-tiles per block
  constexpr int ATPM = KDIM / 32;                     // A tiles per mt row

  const int q = gridDim.x >> 3;
  const int g = (blockIdx.x & 7) * q + (blockIdx.x >> 3);
  const int slot_nt = g / MAXT;
  const int mt = g % MAXT;
  if (mt >= toff[NE]) return;
  int e = 0;
  while (mt >= toff[e + 1]) ++e;
  const int mtile = mt - toff[e];
  const int cnt_e = cnt[e];
  const int eoff = expoff[e];
  const int ntile = (LAYER == 1) ? slot_nt : (slot_nt >> 1);
  const int split = (LAYER == 1) ? 0 : (slot_nt & 1);

  __shared__ __align__(16) char Alds[2][8192];    // 16 KiB
  __shared__ __align__(16) char Blds[2][16384];   // 32 KiB

  const int tid = threadIdx.x;
  const int lane = tid & 63;
  const int l15 = lane & 15, lhi = lane >> 4;
  const int wn = tid >> 6;                        // 4 waves across N
  const int uw = __builtin_amdgcn_readfirstlane(wn);

  // packed streams (shorts): A tile = 4096, B tile = 8192
  const unsigned short* aP = Apack +
      ((size_t)mt * ATPM + (size_t)split * (KT)) * 4096;
  const unsigned short* bP = Bpack + (size_t)e * (NDIM / 256) * (KDIM / 32) * 8192 +
      ((size_t)ntile * (KDIM / 32) + (size_t)split * KT) * 8192;

  auto stage = [&](int buf, int kt) {
    const unsigned short* ap = aP + (size_t)kt * 4096;
#pragma unroll
    for (int i = 0; i < 2; ++i)
      gload(ap + (i * 256 + tid) * 8, &Alds[buf][0] + i * 4096 + uw * 1024);
    const unsigned short* bp = bP + (size_t)kt * 8192;
#pragma unroll
    for (int i = 0; i < 4; ++i)
      gload(bp + (i * 256 + tid) * 8, &Blds[buf][0] + i * 4096 + uw * 1024);
  };

  f32x4 acc[8][4];
#pragma unroll
  for (int m = 0; m < 8; ++m)
#pragma unroll
    for (int n = 0; n < 4; ++n) acc[m][n] = (f32x4){0.f, 0.f, 0.f, 0.f};

  stage(0, 0);
  __syncthreads();

  for (int kt = 0; kt < KT; ++kt) {
    const int b = kt & 1;
    if (kt + 1 < KT) stage(b ^ 1, kt + 1);
    short8 bfr[4];
#pragma unroll
    for (int n = 0; n < 4; ++n) {
      const int row = wn * 64 + n * 16 + l15;
      bfr[n] = *(const short8*)(&Blds[b][0] + row * 64 + ((lhi ^ sw(row)) << 4));
    }
#pragma unroll
    for (int m = 0; m < 8; ++m) {
      const int row = m * 16 + l15;
      const short8 af = *(const short8*)(&Alds[b][0] + row * 64 + ((lhi ^ sw(row)) << 4));
#pragma unroll
      for (int n = 0; n < 4; ++n)
        acc[m][n] = __builtin_amdgcn_mfma_f32_16x16x32_bf16(af, bfr[n], acc[m][n], 0, 0, 0);
    }
    __syncthreads();
  }

  // epilogue: C/D layout col = lane&15, row = (lane>>4)*4 + j
#pragma unroll
  for (int m = 0; m < 8; ++m) {
#pragma unroll
    for (int j = 0; j < 4; ++j) {
      const int row = m * 16 + lhi * 4 + j;
      if (mtile * 128 + row >= cnt_e) continue;
#pragma unroll
      for (int n = 0; n < 4; ++n) {
        const int col = ntile * 256 + wn * 64 + n * 16 + l15;
        if (LAYER == 1) {
          float val = acc[m][n][j] + bias[e * NDIM + col];
          float gl = 0.5f * val * (1.f + erff(val * 0.70710678118654752f));
          // write in GEMM2's packed-A format: tile (mt, col>>5)
          const size_t byte = ((size_t)mt * 128 + (col >> 5)) * 8192 + row * 64 +
                              ((((col >> 3) & 3) ^ sw(row)) << 4) + (col & 7) * 2;
          *(unsigned short*)((char*)OutP + byte) = (unsigned short)f2bf(gl);
        } else {
          float val = acc[m][n][j] + (split == 0 ? bias[e * NDIM + col] : 0.f);
          const size_t slot = (size_t)(eoff + mtile * 128 + row);
          unsigned short* dst = (split == 0) ? OutP : OutP2;
          dst[slot * D_DIM + col] = (unsigned short)f2bf(val);
        }
      }
    }
  }
}

// ---------------- combine: out[t] = w0*(yA+yB)[s0] + w1*(yA+yB)[s1] ---------
__global__ __launch_bounds__(256) void combine_kernel(
    const unsigned short* __restrict__ ybufA, const unsigned short* __restrict__ ybufB,
    const float* __restrict__ pairw, const int* __restrict__ pairslot,
    float* __restrict__ out)
{
  const int t = blockIdx.x;
  const int tid = threadIdx.x;
  const float w0 = pairw[t * 2], w1 = pairw[t * 2 + 1];
  const int s0 = pairslot[t * 2], s1 = pairslot[t * 2 + 1];
  const short4v a0 = ((const short4v*)(ybufA + (size_t)s0 * D_DIM))[tid];
  const short4v b0 = ((const short4v*)(ybufB + (size_t)s0 * D_DIM))[tid];
  const short4v a1 = ((const short4v*)(ybufA + (size_t)s1 * D_DIM))[tid];
  const short4v b1 = ((const short4v*)(ybufB + (size_t)s1 * D_DIM))[tid];
  float4 o;
  o.x = w0 * (bf2f(a0.x) + bf2f(b0.x)) + w1 * (bf2f(a1.x) + bf2f(b1.x));
  o.y = w0 * (bf2f(a0.y) + bf2f(b0.y)) + w1 * (bf2f(a1.y) + bf2f(b1.y));
  o.z = w0 * (bf2f(a0.z) + bf2f(b0.z)) + w1 * (bf2f(a1.z) + bf2f(b1.z));
  o.w = w0 * (bf2f(a0.w) + bf2f(b0.w)) + w1 * (bf2f(a1.w) + bf2f(b1.w));
  ((float4*)(out + (size_t)t * D_DIM))[tid] = o;
}

// ---------------- launch ----------------------------------------------------
extern "C" void kernel_launch(void* const* d_in, const int* in_sizes, int n_in,
                              void* d_out, int out_size, void* d_ws, size_t ws_size,
                              hipStream_t stream)
{
  const float* X  = (const float*)d_in[0];
  const float* Wg = (const float*)d_in[1];
  const float* bg = (const float*)d_in[2];
  const float* W1 = (const float*)d_in[3];
  const float* b1 = (const float*)d_in[4];
  const float* W2 = (const float*)d_in[5];
  const float* b2 = (const float*)d_in[6];
  float* out = (float*)d_out;

  char* ws = (char*)d_ws;
  size_t off = 0;
  auto alloc = [&](size_t sz) {
    size_t o = off;
    off = (off + sz + 255) & ~(size_t)255;
    return o;
  };
  int*            cnt      = (int*)(ws + alloc(NE * sizeof(int)));
  int*            expoff   = (int*)(ws + alloc(NE * sizeof(int)));
  int*            toff     = (int*)(ws + alloc((NE + 1) * sizeof(int)));
  int*            bucket   = (int*)(ws + alloc((size_t)NE * CAP * sizeof(int)));
  float*          pairw    = (float*)(ws + alloc((size_t)N_TOK * 2 * sizeof(float)));
  int*            pairslot = (int*)(ws + alloc((size_t)N_TOK * 2 * sizeof(int)));
  unsigned short* W1p      = (unsigned short*)(ws + alloc((size_t)NE * D_DIM * F_DIM * 2));
  unsigned short* W2p      = (unsigned short*)(ws + alloc((size_t)NE * D_DIM * F_DIM * 2));
  unsigned short* XbP      = (unsigned short*)(ws + alloc((size_t)MAXT * 32 * 8192));
  unsigned short* hmidP    = (unsigned short*)(ws + alloc((size_t)MAXT * 128 * 8192));
  unsigned short* ybufB    = (unsigned short*)(ws + alloc((size_t)(N_TOK * 2 + 256) * D_DIM * 2));
  unsigned short* ybufA    = W1p;   // W1p dead after GEMM1

  hipMemsetAsync(cnt, 0, NE * sizeof(int), stream);

  pack_kernel<<<dim3(F_DIM / 64, D_DIM / 64, NE), 256, 0, stream>>>(
      W1, W1p, D_DIM, F_DIM);
  pack_kernel<<<dim3(D_DIM / 64, F_DIM / 64, NE), 256, 0, stream>>>(
      W2, W2p, F_DIM, D_DIM);
  gate_kernel<<<N_TOK, 256, 0, stream>>>(X, Wg, bg, cnt, bucket, pairw);
  prefix_kernel<<<1, 64, 0, stream>>>(cnt, expoff, toff);
  fillslot_kernel<<<NE, 256, 0, stream>>>(cnt, expoff, bucket, pairslot);
  pregather_kernel<<<dim3(MAXT, 4), 256, 0, stream>>>(X, cnt, toff, bucket, XbP);

  moe_gemm<1><<<MAXT * (F_DIM / 256), 256, 0, stream>>>(   // 2176 blocks (%8==0)
      XbP, W1p, b1, cnt, expoff, toff, hmidP, nullptr);
  moe_gemm<2><<<MAXT * (D_DIM / 256) * 2, 256, 0, stream>>>( // 1088 blocks (%8==0)
      hmidP, W2p, b2, cnt, expoff, toff, ybufA, ybufB);
  combine_kernel<<<N_TOK, 256, 0, stream>>>(ybufA, ybufB, pairw, pairslot, out);
}

// Round 11
// 1159.908 us; speedup vs baseline: 1.3656x; 1.3656x over previous
//
#include <hip/hip_runtime.h>
#include <hip/hip_bf16.h>
#include <cstdint>
#include <math.h>

#define N_TOK 8192
#define D_DIM 1024
#define F_DIM 4096
#define NE 8
#define CAP 8192
#define MAXT 72    // max sum_e ceil(cnt_e/256) = 71, padded

typedef __attribute__((ext_vector_type(8))) short short8;
typedef __attribute__((ext_vector_type(4))) short short4v;
typedef __attribute__((ext_vector_type(4))) float f32x4;

__device__ __forceinline__ short f2bf(float f) {
  __bf16 b = (__bf16)f;
  return *(short*)&b;
}
__device__ __forceinline__ float bf2f(short u) {
  union { unsigned int i; float f; } c;
  c.i = ((unsigned int)(unsigned short)u) << 16;
  return c.f;
}
__device__ __forceinline__ void gload(const void* g, void* l) {
  __builtin_amdgcn_global_load_lds(
      (const __attribute__((address_space(1))) uint32_t*)g,
      (__attribute__((address_space(3))) uint32_t*)l, 16, 0, 0);
}

// ---------------- gating + fused X->bf16 ------------------------------------
__global__ __launch_bounds__(256) void gate_kernel(
    const float* __restrict__ X, const float* __restrict__ Wg,
    const float* __restrict__ bg, int* __restrict__ cnt,
    int* __restrict__ bucket, float* __restrict__ pairw,
    unsigned short* __restrict__ Xb)
{
  const int token = blockIdx.x;
  const int tid = threadIdx.x;
  const float4* x4 = (const float4*)(X + (size_t)token * D_DIM);
  const float4* wg4 = (const float4*)Wg;
  float part[NE];
#pragma unroll
  for (int e = 0; e < NE; ++e) part[e] = 0.f;
  const float4 xv = x4[tid];
#pragma unroll
  for (int e = 0; e < NE; ++e) {
    const float4 wv = wg4[e * (D_DIM / 4) + tid];
    part[e] = fmaf(xv.x, wv.x, fmaf(xv.y, wv.y, fmaf(xv.z, wv.z, fmaf(xv.w, wv.w, part[e]))));
  }
  short4v o;
  o.x = f2bf(xv.x); o.y = f2bf(xv.y); o.z = f2bf(xv.z); o.w = f2bf(xv.w);
  ((short4v*)(Xb + (size_t)token * D_DIM))[tid] = o;

#pragma unroll
  for (int e = 0; e < NE; ++e) {
#pragma unroll
    for (int off = 32; off > 0; off >>= 1) part[e] += __shfl_down(part[e], off);
  }
  __shared__ float wsum[4][NE];
  const int wave = tid >> 6;
  if ((tid & 63) == 0) {
#pragma unroll
    for (int e = 0; e < NE; ++e) wsum[wave][e] = part[e];
  }
  __syncthreads();
  if (tid == 0) {
    float lg[NE];
#pragma unroll
    for (int e = 0; e < NE; ++e)
      lg[e] = wsum[0][e] + wsum[1][e] + wsum[2][e] + wsum[3][e] + bg[e];
    int e0 = 0;
#pragma unroll
    for (int e = 1; e < NE; ++e) if (lg[e] > lg[e0]) e0 = e;     // jax tie-break: lower idx
    int e1 = (e0 == 0) ? 1 : 0;
#pragma unroll
    for (int e = 0; e < NE; ++e) if (e != e0 && lg[e] > lg[e1]) e1 = e;
    float p1 = expf(lg[e1] - lg[e0]);            // p0 = 1; softmax denom cancels
    float inv = 1.f / (1.f + p1);
    pairw[token * 2]     = inv;
    pairw[token * 2 + 1] = p1 * inv;
    int pos0 = atomicAdd(&cnt[e0], 1);
    bucket[e0 * CAP + pos0] = token * 2;
    int pos1 = atomicAdd(&cnt[e1], 1);
    bucket[e1 * CAP + pos1] = token * 2 + 1;
  }
}

// ---------------- prefix sums (row offsets + 256-row tile offsets) ----------
__global__ void prefix_kernel(const int* __restrict__ cnt,
                              int* __restrict__ expoff, int* __restrict__ toff)
{
  if (threadIdx.x == 0 && blockIdx.x == 0) {
    int s = 0, t = 0;
#pragma unroll
    for (int e = 0; e < NE; ++e) {
      expoff[e] = s;
      toff[e] = t;
      s += cnt[e];
      t += (cnt[e] + 255) >> 8;
    }
    toff[NE] = t;
  }
}

// ---------------- inverse map: pair -> slot ---------------------------------
__global__ __launch_bounds__(256) void fillslot_kernel(
    const int* __restrict__ cnt, const int* __restrict__ expoff,
    const int* __restrict__ bucket, int* __restrict__ pairslot)
{
  const int e = blockIdx.x;
  const int n = cnt[e], off = expoff[e];
  for (int p = threadIdx.x; p < n; p += 256)
    pairslot[bucket[e * CAP + p]] = off + p;
}

// ---------------- pack weights: fp32 [R=K][C=N] -> 16KB linear B tiles ------
// Tile (nt=n>>7, kt=k>>6): byte = r*128 + ((c ^ (r&7))<<4) + (k&7)*2 with
// r = n&127, c = (k>>3)&7  -- exactly the LDS image the GEMM reads, so B
// staging is a pure linear 16 KB stream (R9-proven; 0 read conflicts).
__global__ __launch_bounds__(256) void pack_kernel(
    const float* __restrict__ src, unsigned short* __restrict__ dst, int R, int C)
{
  __shared__ float tileT[64][68];
  const int ez = blockIdx.z;
  src += (size_t)ez * R * C;
  char* dbytes = (char*)dst + (size_t)ez * R * C * 2;
  const int c0 = blockIdx.x * 64, r0 = blockIdx.y * 64;
  const int tid = threadIdx.x;
  const int cx = tid & 15;
  const int ry = tid >> 4;
#pragma unroll
  for (int i = 0; i < 4; ++i) {
    const int row = ry + i * 16;
    const float4 v = *(const float4*)(src + (size_t)(r0 + row) * C + c0 + cx * 4);
    tileT[cx * 4 + 0][row] = v.x;
    tileT[cx * 4 + 1][row] = v.y;
    tileT[cx * 4 + 2][row] = v.z;
    tileT[cx * 4 + 3][row] = v.w;
  }
  __syncthreads();
#pragma unroll
  for (int i = 0; i < 4; ++i) {
    const int cc = ry + i * 16;
    const int n = c0 + cc;                 // N dim (tile row)
    const int k = r0 + cx * 4;             // K dim
    const float4 v = *(const float4*)(&tileT[cc][cx * 4]);
    short4v o;
    o.x = f2bf(v.x); o.y = f2bf(v.y); o.z = f2bf(v.z); o.w = f2bf(v.w);
    const int nt = n >> 7, r = n & 127;
    const int kt = k >> 6, c = (k >> 3) & 7;
    const size_t byte = ((size_t)nt * (R >> 6) + kt) * 16384 +
                        r * 128 + ((c ^ (r & 7)) << 4) + (k & 7) * 2;
    *(short4v*)(dbytes + byte) = o;
  }
}

// ---------------- grouped expert GEMM: 256x128xBK64, single-buf, DMA --------
// 4 waves (2M x 2N), wave = 128x64, acc[8][4] (128 VGPR). LDS 49 KB single-
// buffered -> 2-3 blocks/CU; cross-block overlap hides the per-K-tile drain
// (R1-proven loop shape). Ratio BM*BN/(BM+BN)=85 cuts staged demand 25% vs
// 128^2. Staging: global_load_lds w16, uniform dest; A source pre-swizzled
// (R7, 0 conflicts), B = packed linear tiles (R9).
// LAYER 1: hmid[slot] = gelu(Xb[tok] @ W1p + b1)   (K=1024, A gathered)
// LAYER 2: ybuf[slot] = hmid[slot] @ W2p + b2      (K=4096, A contiguous)
template<int LAYER>
__global__ __launch_bounds__(256) void moe_gemm(
    const unsigned short* __restrict__ Abase,
    const unsigned short* __restrict__ Bpack,
    const float* __restrict__ bias,
    const int* __restrict__ cnt,
    const int* __restrict__ expoff,
    const int* __restrict__ toff,
    const int* __restrict__ bucket,
    unsigned short* __restrict__ Obuf)      // hmid (L1) or ybuf (L2)
{
  constexpr int BM = 256, BN = 128, BK = 64;
  constexpr int KDIM = (LAYER == 1) ? D_DIM : F_DIM;
  constexpr int NDIM = (LAYER == 1) ? F_DIM : D_DIM;
  constexpr int KT = KDIM / BK;            // 16 or 64
  constexpr int NT = NDIM / BN;            // 32 or 8

  // XCD chunk decode, mt fastest (B-panel L2 reuse within a chunk)
  const int q = gridDim.x >> 3;
  const int g = (blockIdx.x & 7) * q + (blockIdx.x >> 3);
  const int ntile = g / MAXT;
  const int mt = g % MAXT;
  if (mt >= toff[NE]) return;
  int e = 0;
  while (mt >= toff[e + 1]) ++e;
  const int mtile = mt - toff[e];
  const int cnt_e = cnt[e];
  const int eoff = expoff[e];

  __shared__ __align__(16) char Alds[BM * 128];   // 32 KiB (single buffer)
  __shared__ __align__(16) char Blds[BN * 128];   // 16 KiB (single buffer)
  __shared__ int rowpair[BM];

  const int tid = threadIdx.x;
  const int lane = tid & 63;
  const int l15 = lane & 15, lhi = lane >> 4;
  const int wid = tid >> 6;
  const int uw = __builtin_amdgcn_readfirstlane(wid);
  const int wm = wid >> 1, wn = wid & 1;          // 2M x 2N waves

  if (LAYER == 1) {
    if (tid < BM) {
      int pos = mtile * BM + tid;
      rowpair[tid] = (pos < cnt_e) ? bucket[e * CAP + pos] : -1;
    }
    __syncthreads();
  }

  // A: chunk ci = i*256+tid (i=0..7); r = ci>>3, c = ci&7; source column
  // pre-XOR-swizzled sc = c^(r&7) so linear LDS dest == swizzled read image.
  const unsigned short* a_src[8];
#pragma unroll
  for (int i = 0; i < 8; ++i) {
    int ci = i * 256 + tid;
    int r = ci >> 3, c = ci & 7;
    int sc = c ^ (r & 7);
    size_t arow;
    if (LAYER == 1) {
      int pair = rowpair[r];
      arow = (pair < 0) ? 0 : (size_t)(pair >> 1);
    } else {
      arow = (size_t)(eoff + mtile * BM + r);      // contiguous slot rows
    }
    a_src[i] = Abase + arow * KDIM + sc * 8;
  }
  // B: packed linear tiles (swizzle baked in by pack_kernel)
  const unsigned short* bP = Bpack + (size_t)e * NDIM * KDIM +
      ((size_t)ntile * KT) * 8192;

  auto stage = [&](int kt) {
#pragma unroll
    for (int i = 0; i < 8; ++i)
      gload(a_src[i] + kt * BK, &Alds[0] + i * 4096 + uw * 1024);
    const unsigned short* bp = bP + (size_t)kt * 8192;
#pragma unroll
    for (int i = 0; i < 4; ++i)
      gload(bp + (i * 256 + tid) * 8, &Blds[0] + i * 4096 + uw * 1024);
  };

  f32x4 acc[8][4];
#pragma unroll
  for (int m = 0; m < 8; ++m)
#pragma unroll
    for (int n = 0; n < 4; ++n) acc[m][n] = (f32x4){0.f, 0.f, 0.f, 0.f};

  for (int kt = 0; kt < KT; ++kt) {
    stage(kt);
    __syncthreads();                 // vmcnt(0)+lgkmcnt(0) drain + barrier
#pragma unroll
    for (int kk = 0; kk < 2; ++kk) {
      const int c16 = kk * 4 + lhi;
      short8 bfr[4];
#pragma unroll
      for (int n = 0; n < 4; ++n) {
        int row = wn * 64 + n * 16 + l15;
        bfr[n] = *(const short8*)(&Blds[0] + row * 128 + ((c16 ^ (row & 7)) * 16));
      }
#pragma unroll
      for (int m = 0; m < 8; ++m) {
        int row = wm * 128 + m * 16 + l15;
        short8 af = *(const short8*)(&Alds[0] + row * 128 + ((c16 ^ (row & 7)) * 16));
#pragma unroll
        for (int n = 0; n < 4; ++n)
          acc[m][n] = __builtin_amdgcn_mfma_f32_16x16x32_bf16(af, bfr[n], acc[m][n], 0, 0, 0);
      }
    }
    __syncthreads();                 // all reads done before restaging
  }

  // epilogue: C/D layout col = lane&15, row = (lane>>4)*4 + j
#pragma unroll
  for (int m = 0; m < 8; ++m) {
#pragma unroll
    for (int j = 0; j < 4; ++j) {
      const int row = wm * 128 + m * 16 + lhi * 4 + j;
      if (mtile * BM + row >= cnt_e) continue;
      const size_t slot = (size_t)(eoff + mtile * BM + row);
#pragma unroll
      for (int n = 0; n < 4; ++n) {
        const int col = ntile * BN + wn * 64 + n * 16 + l15;
        float val = acc[m][n][j] + bias[e * NDIM + col];
        if (LAYER == 1) {
          float gl = 0.5f * val * (1.f + erff(val * 0.70710678118654752f));
          Obuf[slot * F_DIM + col] = (unsigned short)f2bf(gl);
        } else {
          Obuf[slot * D_DIM + col] = (unsigned short)f2bf(val);
        }
      }
    }
  }
}

// ---------------- combine: out[t] = w0*y[slot0] + w1*y[slot1] ---------------
__global__ __launch_bounds__(256) void combine_kernel(
    const unsigned short* __restrict__ ybuf, const float* __restrict__ pairw,
    const int* __restrict__ pairslot, float* __restrict__ out)
{
  const int t = blockIdx.x;
  const int tid = threadIdx.x;
  const float w0 = pairw[t * 2], w1 = pairw[t * 2 + 1];
  const int s0 = pairslot[t * 2], s1 = pairslot[t * 2 + 1];
  const short4v a = ((const short4v*)(ybuf + (size_t)s0 * D_DIM))[tid];
  const short4v b = ((const short4v*)(ybuf + (size_t)s1 * D_DIM))[tid];
  float4 o;
  o.x = w0 * bf2f(a.x) + w1 * bf2f(b.x);
  o.y = w0 * bf2f(a.y) + w1 * bf2f(b.y);
  o.z = w0 * bf2f(a.z) + w1 * bf2f(b.z);
  o.w = w0 * bf2f(a.w) + w1 * bf2f(b.w);
  ((float4*)(out + (size_t)t * D_DIM))[tid] = o;
}

// ---------------- launch ----------------------------------------------------
extern "C" void kernel_launch(void* const* d_in, const int* in_sizes, int n_in,
                              void* d_out, int out_size, void* d_ws, size_t ws_size,
                              hipStream_t stream)
{
  const float* X  = (const float*)d_in[0];
  const float* Wg = (const float*)d_in[1];
  const float* bg = (const float*)d_in[2];
  const float* W1 = (const float*)d_in[3];
  const float* b1 = (const float*)d_in[4];
  const float* W2 = (const float*)d_in[5];
  const float* b2 = (const float*)d_in[6];
  float* out = (float*)d_out;

  char* ws = (char*)d_ws;
  size_t off = 0;
  auto alloc = [&](size_t sz) {
    size_t o = off;
    off = (off + sz + 255) & ~(size_t)255;
    return o;
  };
  int*            cnt      = (int*)(ws + alloc(NE * sizeof(int)));
  int*            expoff   = (int*)(ws + alloc(NE * sizeof(int)));
  int*            toff     = (int*)(ws + alloc((NE + 1) * sizeof(int)));
  int*            bucket   = (int*)(ws + alloc((size_t)NE * CAP * sizeof(int)));
  float*          pairw    = (float*)(ws + alloc((size_t)N_TOK * 2 * sizeof(float)));
  int*            pairslot = (int*)(ws + alloc((size_t)N_TOK * 2 * sizeof(int)));
  unsigned short* Xb       = (unsigned short*)(ws + alloc((size_t)N_TOK * D_DIM * 2));
  unsigned short* W1p      = (unsigned short*)(ws + alloc((size_t)NE * D_DIM * F_DIM * 2));
  unsigned short* W2p      = (unsigned short*)(ws + alloc((size_t)NE * D_DIM * F_DIM * 2));
  unsigned short* hmid     = (unsigned short*)(ws + alloc((size_t)(N_TOK * 2 + 256) * F_DIM * 2));
  unsigned short* ybuf     = W1p;   // W1p dead after GEMM1

  hipMemsetAsync(cnt, 0, NE * sizeof(int), stream);

  pack_kernel<<<dim3(F_DIM / 64, D_DIM / 64, NE), 256, 0, stream>>>(
      W1, W1p, D_DIM, F_DIM);
  pack_kernel<<<dim3(D_DIM / 64, F_DIM / 64, NE), 256, 0, stream>>>(
      W2, W2p, F_DIM, D_DIM);
  gate_kernel<<<N_TOK, 256, 0, stream>>>(X, Wg, bg, cnt, bucket, pairw, Xb);
  prefix_kernel<<<1, 64, 0, stream>>>(cnt, expoff, toff);
  fillslot_kernel<<<NE, 256, 0, stream>>>(cnt, expoff, bucket, pairslot);

  moe_gemm<1><<<MAXT * (F_DIM / 128), 256, 0, stream>>>(   // 2304 blocks (%8==0)
      Xb, W1p, b1, cnt, expoff, toff, bucket, hmid);
  moe_gemm<2><<<MAXT * (D_DIM / 128), 256, 0, stream>>>(   // 576 blocks (%8==0)
      hmid, W2p, b2, cnt, expoff, toff, bucket, ybuf);
  combine_kernel<<<N_TOK, 256, 0, stream>>>(ybuf, pairw, pairslot, out);
}